// Round 4
// baseline (290.191 us; speedup 1.0000x reference)
//
#include <hip/hip_runtime.h>

#define N_NODES  131072
#define N_GRAPHS 4096
#define HID      512

typedef float  f32x4  __attribute__((ext_vector_type(4)));
typedef __bf16 bf16x8 __attribute__((ext_vector_type(8)));
typedef unsigned short u16x8 __attribute__((ext_vector_type(8)));

__device__ __forceinline__ unsigned short f2bf(float f) {
  unsigned int u = __builtin_bit_cast(unsigned int, f);
  u += 0x7FFFu + ((u >> 16) & 1u);   // round-to-nearest-even
  return (unsigned short)(u >> 16);
}
__device__ __forceinline__ f32x4 mfma_bf16(bf16x8 a, bf16x8 b, f32x4 c) {
  return __builtin_amdgcn_mfma_f32_16x16x32_bf16(a, b, c, 0, 0, 0);
}

// ---------- bucket: sort graphs by branch ----------
__global__ __launch_bounds__(256) void bucket_kernel(
    const int* __restrict__ dsid, int* __restrict__ perm, int* __restrict__ meta) {
  __shared__ int cnt[4], base[4], off[4];
  int t = threadIdx.x;
  if (t < 4) { cnt[t] = 0; off[t] = 0; }
  __syncthreads();
  for (int g = t; g < N_GRAPHS; g += 256) atomicAdd(&cnt[dsid[g]], 1);
  __syncthreads();
  if (t == 0) {
    int s = 0;
    for (int b = 0; b < 4; ++b) { base[b] = s; s += cnt[b]; meta[b] = cnt[b]; }
  }
  __syncthreads();
  for (int g = t; g < N_GRAPHS; g += 256) {
    int b = dsid[g];
    int p = base[b] + atomicAdd(&off[b], 1);
    perm[p] = g;
  }
}

// ---------- prep: W[b][k][n] fp32 -> fragment-ordered bf16 -------------------
// Layout: [b][hf=32][kk=16][lane=64][e=8]; value = W[k=kk*32+(lane>>4)*8+e][n=hf*16+(lane&15)]
__global__ __launch_bounds__(256) void prep_wf_kernel(
    const float* __restrict__ Wn1, const float* __restrict__ Ws,
    unsigned short* __restrict__ W1Tf, unsigned short* __restrict__ WsTf) {
  __shared__ unsigned short lt[8192];
  const int bid = blockIdx.x;          // 256 blocks
  const int which = bid >> 7;
  const int b  = (bid >> 5) & 3;
  const int hf = bid & 31;
  const float* src = (which ? Ws : Wn1) + (size_t)b * 512 * 512 + hf * 16;
  unsigned short* dst = (which ? WsTf : W1Tf) + (size_t)(b * 32 + hf) * 8192;
  const int t = threadIdx.x;
  for (int i = t; i < 8192; i += 256) {
    int k = i >> 4;
    int n = i & 15;
    float v = src[(size_t)k * 512 + n];
    int kk = k >> 5, lane = n + ((k >> 3) & 3) * 16, e = k & 7;
    lt[(kk * 64 + lane) * 8 + e] = f2bf(v);
  }
  __syncthreads();
  u16x8* d8 = (u16x8*)dst;
  const u16x8* s8 = (const u16x8*)lt;
  for (int i = t; i < 1024; i += 256) d8[i] = s8[i];
}

// ---------- prep: Wg (4,512,100) -> WgT [b][128][512] bf16 zero-pad ----------
__global__ __launch_bounds__(256) void prep_wg_kernel(
    const float* __restrict__ Wg, unsigned short* __restrict__ WgT) {
  int idx = blockIdx.x * 256 + threadIdx.x;   // 1024 blocks
  int b = idx >> 16;
  int r = (idx >> 9) & 127;
  int k = idx & 511;
  float v = (r < 100) ? Wg[(b * 512 + k) * 100 + r] : 0.f;
  WgT[idx] = f2bf(v);
}

// ---------- node kernel: chunked pipeline (BK=128 x 4), pool fused ----------
// 512 threads = 8 waves. M=64 rows (2 graphs, branch-uniform).
// Per chunk: reg-prefetch next x chunk -> convert -> LDS frag write -> pool shfl
// -> barrier -> xg finalize -> 4x16 MFMA.  One barrier per chunk.
#define NT_MAX 2050
__global__ __launch_bounds__(512, 4) void node_kernel(
    const float* __restrict__ x,
    const int* __restrict__ meta,
    const int* __restrict__ perm,
    const unsigned short* __restrict__ W1Tf,
    const float* __restrict__ bn1,
    const float* __restrict__ Wn2,
    const float* __restrict__ bn2,
    unsigned short* __restrict__ xg,
    float* __restrict__ n_head,
    float* __restrict__ n_var) {
  __shared__ __align__(16) unsigned short xfrag[2][8192];  // 2 x 16 KB
  __shared__ __align__(16) float psum[2][8][128];          // 8 KB
  // epilogue reduction buffer aliased over xfrag[0] (12 KB <= 16 KB)

  const int4 cvv = *(const int4*)meta;
  const int cnts[4] = {cvv.x, cvv.y, cvv.z, cvv.w};
  int i = blockIdx.x, branch = -1, permOff = 0, nvalid = 0, pb = 0;
  for (int b = 0; b < 4; ++b) {
    int nt = (cnts[b] + 1) >> 1;
    if (branch < 0 && i < nt) { branch = b; permOff = pb + i * 2; nvalid = min(2, cnts[b] - i * 2); }
    if (branch < 0) i -= nt;
    pb += cnts[b];
  }
  if (branch < 0) return;

  const int t    = threadIdx.x;
  const int lane = t & 63;
  const int w    = t >> 6;
  const int l15  = lane & 15;
  const int l4   = lane >> 4;

  const int g0 = perm[permOff];
  const int g1 = perm[permOff + (nvalid > 1 ? 1 : 0)];

  // staging geometry: thread -> graph sg, row pair (qq, qq+16), col octet o
  const int sg = t >> 8;
  const int qq = (t >> 4) & 15;
  const int o  = t & 15;
  const int gsrc = sg ? g1 : g0;
  const float* srow0 = x + ((size_t)gsrc * 32 + qq) * HID + o * 8;
  const float* srow1 = srow0 + 16 * HID;
  // LDS fragment write positions (elements)
  const int kkl = o >> 2, wl4 = o & 3;
  const int wpos0 = ((sg * 2 + 0) * 4 + kkl) * 512 + (wl4 * 16 + qq) * 8;
  const int wpos1 = ((sg * 2 + 1) * 4 + kkl) * 512 + (wl4 * 16 + qq) * 8;

  const unsigned short* wbase = W1Tf + ((size_t)(branch * 32 + w * 4)) * 8192 + lane * 8;

  f32x4 acc[4][4];
  #pragma unroll
  for (int m = 0; m < 4; ++m)
    #pragma unroll
    for (int n = 0; n < 4; ++n) acc[m][n] = (f32x4)0.f;

  // prologue: load chunk 0
  float4 p0 = *(const float4*)(srow0);
  float4 p1 = *(const float4*)(srow0 + 4);
  float4 p2 = *(const float4*)(srow1);
  float4 p3 = *(const float4*)(srow1 + 4);

  #pragma unroll
  for (int c = 0; c < 4; ++c) {
    // convert + fragment write (ds_write_b128 x2, lane-linear)
    u16x8 ua, ub;
    ua[0]=f2bf(p0.x); ua[1]=f2bf(p0.y); ua[2]=f2bf(p0.z); ua[3]=f2bf(p0.w);
    ua[4]=f2bf(p1.x); ua[5]=f2bf(p1.y); ua[6]=f2bf(p1.z); ua[7]=f2bf(p1.w);
    ub[0]=f2bf(p2.x); ub[1]=f2bf(p2.y); ub[2]=f2bf(p2.z); ub[3]=f2bf(p2.w);
    ub[4]=f2bf(p3.x); ub[5]=f2bf(p3.y); ub[6]=f2bf(p3.z); ub[7]=f2bf(p3.w);
    *(u16x8*)&xfrag[c & 1][wpos0] = ua;
    *(u16x8*)&xfrag[c & 1][wpos1] = ub;

    // pool partials: sum the 2 rows, reduce over qq&3 (lane bits 4,5)
    float s[8];
    s[0]=p0.x+p2.x; s[1]=p0.y+p2.y; s[2]=p0.z+p2.z; s[3]=p0.w+p2.w;
    s[4]=p1.x+p3.x; s[5]=p1.y+p3.y; s[6]=p1.z+p3.z; s[7]=p1.w+p3.w;
    #pragma unroll
    for (int j = 0; j < 8; ++j) {
      s[j] += __shfl_xor(s[j], 16);
      s[j] += __shfl_xor(s[j], 32);
    }
    if (lane < 16) {
      float4 a4; a4.x=s[0]; a4.y=s[1]; a4.z=s[2]; a4.w=s[3];
      float4 b4; b4.x=s[4]; b4.y=s[5]; b4.z=s[6]; b4.w=s[7];
      *(float4*)&psum[c & 1][w][lane * 8]     = a4;
      *(float4*)&psum[c & 1][w][lane * 8 + 4] = b4;
    }

    // issue next chunk's loads before the barrier (hide under barrier+MFMA)
    if (c < 3) {
      p0 = *(const float4*)(srow0 + (c + 1) * 128);
      p1 = *(const float4*)(srow0 + (c + 1) * 128 + 4);
      p2 = *(const float4*)(srow1 + (c + 1) * 128);
      p3 = *(const float4*)(srow1 + (c + 1) * 128 + 4);
    }
    __syncthreads();

    // finalize xg columns of chunk c (deterministic 4-wave sum)
    if (t < 256) {
      int gg = t >> 7, cc = t & 127;
      if (gg == 0 || nvalid > 1) {
        float sv = psum[c & 1][gg * 4 + 0][cc] + psum[c & 1][gg * 4 + 1][cc]
                 + psum[c & 1][gg * 4 + 2][cc] + psum[c & 1][gg * 4 + 3][cc];
        xg[(size_t)(gg ? g1 : g0) * HID + c * 128 + cc] = f2bf(sv * (1.f / 32.f));
      }
    }

    // MFMA on chunk c
    __builtin_amdgcn_s_setprio(1);
    #pragma unroll
    for (int kk = 0; kk < 4; ++kk) {
      bf16x8 af[4];
      #pragma unroll
      for (int m = 0; m < 4; ++m)
        af[m] = *(const bf16x8*)(wbase + (size_t)(m * 16 + c * 4 + kk) * 512);
      bf16x8 bfr[4];
      #pragma unroll
      for (int n = 0; n < 4; ++n)
        bfr[n] = *(const bf16x8*)&xfrag[c & 1][(n * 4 + kk) * 512 + lane * 8];
      #pragma unroll
      for (int m = 0; m < 4; ++m)
        #pragma unroll
        for (int n = 0; n < 4; ++n)
          acc[m][n] = mfma_bf16(af[m], bfr[n], acc[m][n]);
    }
    __builtin_amdgcn_s_setprio(0);
  }

  // ---- fused stage 2: per-lane fp32 dot with Wn2 over this lane's 16 hcols ----
  float part[4][6];
  #pragma unroll
  for (int n = 0; n < 4; ++n)
    #pragma unroll
    for (int j = 0; j < 6; ++j) part[n][j] = 0.f;
  const float* W2 = Wn2 + branch * HID * 6;
  const float* B1 = bn1 + branch * HID;
  #pragma unroll
  for (int m = 0; m < 4; ++m) {
    #pragma unroll
    for (int r = 0; r < 4; ++r) {
      int hcol = w * 64 + m * 16 + l4 * 4 + r;
      float b1 = B1[hcol];
      float w2[6];
      #pragma unroll
      for (int j = 0; j < 6; ++j) w2[j] = W2[hcol * 6 + j];
      #pragma unroll
      for (int n = 0; n < 4; ++n) {
        float h = fmaxf(acc[m][n][r] + b1, 0.f);
        #pragma unroll
        for (int j = 0; j < 6; ++j) part[n][j] += h * w2[j];
      }
    }
  }
  #pragma unroll
  for (int n = 0; n < 4; ++n)
    #pragma unroll
    for (int j = 0; j < 6; ++j) {
      part[n][j] += __shfl_xor(part[n][j], 16);
      part[n][j] += __shfl_xor(part[n][j], 32);
    }
  // cross-wave reduce via LDS aliased over xfrag[0] (safe: all waves passed the
  // last barrier, so chunk-2 reads of xfrag[0] are done; chunk-3 uses xfrag[1])
  float (*red)[64][6] = (float (*)[64][6])&xfrag[0][0];
  if (lane < 16) {
    #pragma unroll
    for (int n = 0; n < 4; ++n)
      #pragma unroll
      for (int j = 0; j < 6; ++j) red[w][n * 16 + l15][j] = part[n][j];
  }
  __syncthreads();
  if (t < 64) {
    int row = t;
    if (row < nvalid * 32) {
      int node = (row < 32 ? g0 : g1) * 32 + (row & 31);
      #pragma unroll
      for (int j = 0; j < 6; ++j) {
        float sv = red[0][row][j] + red[1][row][j] + red[2][row][j] + red[3][row][j]
                 + red[4][row][j] + red[5][row][j] + red[6][row][j] + red[7][row][j]
                 + bn2[branch * 6 + j];
        if (j < 3) n_head[(size_t)node * 3 + j] = sv;
        else       n_var[(size_t)node * 3 + (j - 3)] = sv * sv;
      }
    }
  }
}

// ---------- graph stage-1: hg = relu(xg @ Ws + bs), 64 graphs/block ----------
#define GT_MAX 67
__global__ __launch_bounds__(512, 4) void gstage1_kernel(
    const unsigned short* __restrict__ xg,
    const int* __restrict__ meta,
    const int* __restrict__ perm,
    const unsigned short* __restrict__ WsTf,
    const float* __restrict__ bs_,
    unsigned short* __restrict__ hg) {
  __shared__ __align__(16) unsigned short xtile[4 * 16 * 512];
  __shared__ int gidl[64];

  const int4 cv = *(const int4*)meta;
  const int cnts[4] = {cv.x, cv.y, cv.z, cv.w};

  int i = blockIdx.x, branch = -1, permOff = 0, nvalid = 0, pb = 0;
  for (int b = 0; b < 4; ++b) {
    int gt = (cnts[b] + 63) >> 6;
    if (branch < 0 && i < gt) { branch = b; permOff = pb + i * 64; nvalid = min(64, cnts[b] - i * 64); }
    if (branch < 0) i -= gt;
    pb += cnts[b];
  }
  if (branch < 0) return;

  const int t    = threadIdx.x;
  const int lane = t & 63;
  const int w    = t >> 6;
  const int l15  = lane & 15;
  const int l4   = lane >> 4;

  if (t < 64) gidl[t] = perm[permOff + min(t, nvalid - 1)];
  __syncthreads();

  for (int idx = t; idx < 4096; idx += 512) {
    int row = idx >> 6;
    int c8  = (idx & 63) * 8;
    u16x8 v = *(const u16x8*)&xg[(size_t)gidl[row] * HID + c8];
    int kk = c8 >> 5, ln = (c8 >> 3) & 3;
    *(u16x8*)&xtile[(((row >> 4) * 16 + kk) * 64 + ((row & 15) + ln * 16)) * 8] = v;
  }
  __syncthreads();

  f32x4 acc[4][4];
  #pragma unroll
  for (int m = 0; m < 4; ++m)
    #pragma unroll
    for (int n = 0; n < 4; ++n) acc[m][n] = (f32x4)0.f;

  const unsigned short* wbase = WsTf + ((size_t)(branch * 32 + w * 4)) * 8192 + lane * 8;
  const unsigned short* xbase = xtile + lane * 8;
  #pragma unroll
  for (int kk = 0; kk < 16; ++kk) {
    bf16x8 af[4];
    #pragma unroll
    for (int m = 0; m < 4; ++m)
      af[m] = *(const bf16x8*)(wbase + (m * 16 + kk) * 512);
    bf16x8 bfr[4];
    #pragma unroll
    for (int n = 0; n < 4; ++n)
      bfr[n] = *(const bf16x8*)(xbase + (n * 16 + kk) * 512);
    #pragma unroll
    for (int m = 0; m < 4; ++m)
      #pragma unroll
      for (int n = 0; n < 4; ++n)
        acc[m][n] = mfma_bf16(af[m], bfr[n], acc[m][n]);
  }

  const float* B1 = bs_ + branch * HID;
  #pragma unroll
  for (int m = 0; m < 4; ++m) {
    #pragma unroll
    for (int n = 0; n < 4; ++n) {
      int row = n * 16 + l15;
      if (row < nvalid) {
        int g = gidl[row];
        int hcb = w * 64 + m * 16 + l4 * 4;
        ushort4 hv;
        hv.x = f2bf(fmaxf(acc[m][n][0] + B1[hcb + 0], 0.f));
        hv.y = f2bf(fmaxf(acc[m][n][1] + B1[hcb + 1], 0.f));
        hv.z = f2bf(fmaxf(acc[m][n][2] + B1[hcb + 2], 0.f));
        hv.w = f2bf(fmaxf(acc[m][n][3] + B1[hcb + 3], 0.f));
        *(ushort4*)(hg + (size_t)g * HID + hcb) = hv;
      }
    }
  }
}

// ---------- graph stage-2: og = hg @ Wg[b] + bg, 16 graphs/block -------------
#define G2_MAX 259
__global__ __launch_bounds__(256) void gstage2_kernel(
    const int* __restrict__ meta,
    const int* __restrict__ perm,
    const unsigned short* __restrict__ hg,
    const unsigned short* __restrict__ WgT,
    const float* __restrict__ bg,
    float* __restrict__ g_head,
    float* __restrict__ g_var) {
  __shared__ int gidl[16];
  const int4 cv = *(const int4*)meta;
  const int cnts[4] = {cv.x, cv.y, cv.z, cv.w};

  int i = blockIdx.x, branch = -1, permOff = 0, nvalid = 0, pb = 0;
  for (int b = 0; b < 4; ++b) {
    int gt = (cnts[b] + 15) >> 4;
    if (branch < 0 && i < gt) { branch = b; permOff = pb + i * 16; nvalid = min(16, cnts[b] - i * 16); }
    if (branch < 0) i -= gt;
    pb += cnts[b];
  }
  if (branch < 0) return;

  const int t    = threadIdx.x;
  const int lane = t & 63;
  const int w    = t >> 6;
  const int l15  = lane & 15;
  const int l4   = lane >> 4;

  if (t < 16) gidl[t] = perm[permOff + min(t, nvalid - 1)];
  __syncthreads();

  f32x4 acc2[2];
  acc2[0] = (f32x4)0.f; acc2[1] = (f32x4)0.f;
  const unsigned short* arow = hg + (size_t)gidl[l15] * HID + l4 * 8;
  const unsigned short* brow = WgT + ((size_t)branch * 128 + w * 32 + l15) * 512 + l4 * 8;
  #pragma unroll
  for (int ks = 0; ks < 16; ++ks) {
    bf16x8 a  = *(const bf16x8*)(arow + ks * 32);
    bf16x8 b0 = *(const bf16x8*)(brow + ks * 32);
    bf16x8 b1 = *(const bf16x8*)(brow + 16 * 512 + ks * 32);
    acc2[0] = mfma_bf16(a, b0, acc2[0]);
    acc2[1] = mfma_bf16(a, b1, acc2[1]);
  }
  #pragma unroll
  for (int n2 = 0; n2 < 2; ++n2) {
    int j = w * 32 + n2 * 16 + l15;
    if (j < 100) {
      float bias = bg[branch * 100 + j];
      #pragma unroll
      for (int rr = 0; rr < 4; ++rr) {
        int r = l4 * 4 + rr;
        if (r < nvalid) {
          int g = gidl[r];
          float val = acc2[n2][rr] + bias;
          if (j < 50) g_head[(size_t)g * 50 + j] = val;
          else        g_var[(size_t)g * 50 + (j - 50)] = val * val;
        }
      }
    }
  }
}

extern "C" void kernel_launch(void* const* d_in, const int* in_sizes, int n_in,
                              void* d_out, int out_size, void* d_ws, size_t ws_size,
                              hipStream_t stream) {
  const float* x    = (const float*)d_in[0];
  const float* Ws   = (const float*)d_in[1];
  const float* bs   = (const float*)d_in[2];
  const float* Wg   = (const float*)d_in[3];
  const float* bg   = (const float*)d_in[4];
  const float* Wn1  = (const float*)d_in[5];
  const float* bn1  = (const float*)d_in[6];
  const float* Wn2  = (const float*)d_in[7];
  const float* bn2  = (const float*)d_in[8];
  const int* dsid   = (const int*)d_in[10];

  float* out    = (float*)d_out;
  float* g_head = out;
  float* g_var  = out + (size_t)N_GRAPHS * 50;
  float* n_head = out + (size_t)2 * N_GRAPHS * 50;
  float* n_var  = n_head + (size_t)N_NODES * 3;

  char* ws = (char*)d_ws;
  int* perm = (int*)(ws);                                   // 16384
  int* meta = (int*)(ws + 16384);                           // 256
  unsigned short* W1Tf = (unsigned short*)(ws + 16640);     // 2,097,152
  unsigned short* WsTf = (unsigned short*)(ws + 2113792);   // 2,097,152
  unsigned short* WgT  = (unsigned short*)(ws + 4210944);   // 524,288
  unsigned short* xg   = (unsigned short*)(ws + 4735232);   // 4,194,304
  unsigned short* hg   = (unsigned short*)(ws + 8929536);   // 4,194,304
  if (ws_size < 13123840) return;

  bucket_kernel<<<dim3(1), dim3(256), 0, stream>>>(dsid, perm, meta);
  prep_wf_kernel<<<dim3(256), dim3(256), 0, stream>>>(Wn1, Ws, W1Tf, WsTf);
  prep_wg_kernel<<<dim3(1024), dim3(256), 0, stream>>>(Wg, WgT);
  node_kernel<<<dim3(NT_MAX), dim3(512), 0, stream>>>(
      x, meta, perm, W1Tf, bn1, Wn2, bn2, xg, n_head, n_var);
  gstage1_kernel<<<dim3(GT_MAX), dim3(512), 0, stream>>>(
      xg, meta, perm, WsTf, bs, hg);
  gstage2_kernel<<<dim3(G2_MAX), dim3(256), 0, stream>>>(
      meta, perm, hg, WgT, bg, g_head, g_var);
}

// Round 5
// 220.565 us; speedup vs baseline: 1.3157x; 1.3157x over previous
//
#include <hip/hip_runtime.h>

#define N_NODES  131072
#define N_GRAPHS 4096
#define HID      512

typedef float  f32x4  __attribute__((ext_vector_type(4)));
typedef __bf16 bf16x8 __attribute__((ext_vector_type(8)));
typedef unsigned short u16x8 __attribute__((ext_vector_type(8)));

__device__ __forceinline__ unsigned short f2bf(float f) {
  unsigned int u = __builtin_bit_cast(unsigned int, f);
  u += 0x7FFFu + ((u >> 16) & 1u);   // round-to-nearest-even
  return (unsigned short)(u >> 16);
}
__device__ __forceinline__ f32x4 mfma_bf16(bf16x8 a, bf16x8 b, f32x4 c) {
  return __builtin_amdgcn_mfma_f32_16x16x32_bf16(a, b, c, 0, 0, 0);
}

// ---------- bucket: sort graphs by branch ----------
__global__ __launch_bounds__(256) void bucket_kernel(
    const int* __restrict__ dsid, int* __restrict__ perm, int* __restrict__ meta) {
  __shared__ int cnt[4], base[4], off[4];
  int t = threadIdx.x;
  if (t < 4) { cnt[t] = 0; off[t] = 0; }
  __syncthreads();
  for (int g = t; g < N_GRAPHS; g += 256) atomicAdd(&cnt[dsid[g]], 1);
  __syncthreads();
  if (t == 0) {
    int s = 0;
    for (int b = 0; b < 4; ++b) { base[b] = s; s += cnt[b]; meta[b] = cnt[b]; }
  }
  __syncthreads();
  for (int g = t; g < N_GRAPHS; g += 256) {
    int b = dsid[g];
    int p = base[b] + atomicAdd(&off[b], 1);
    perm[p] = g;
  }
}

// ---------- prep: W[b][k][n] fp32 -> fragment-ordered bf16 -------------------
// Layout: [b][hf=32][kk=16][lane=64][e=8]; value = W[k=kk*32+(lane>>4)*8+e][n=hf*16+(lane&15)]
__global__ __launch_bounds__(256) void prep_wf_kernel(
    const float* __restrict__ Wn1, const float* __restrict__ Ws,
    unsigned short* __restrict__ W1Tf, unsigned short* __restrict__ WsTf) {
  __shared__ unsigned short lt[8192];
  const int bid = blockIdx.x;          // 256 blocks
  const int which = bid >> 7;
  const int b  = (bid >> 5) & 3;
  const int hf = bid & 31;
  const float* src = (which ? Ws : Wn1) + (size_t)b * 512 * 512 + hf * 16;
  unsigned short* dst = (which ? WsTf : W1Tf) + (size_t)(b * 32 + hf) * 8192;
  const int t = threadIdx.x;
  for (int i = t; i < 8192; i += 256) {
    int k = i >> 4;
    int n = i & 15;
    float v = src[(size_t)k * 512 + n];
    int kk = k >> 5, lane = n + ((k >> 3) & 3) * 16, e = k & 7;
    lt[(kk * 64 + lane) * 8 + e] = f2bf(v);
  }
  __syncthreads();
  u16x8* d8 = (u16x8*)dst;
  const u16x8* s8 = (const u16x8*)lt;
  for (int i = t; i < 1024; i += 256) d8[i] = s8[i];
}

// ---------- prep: Wg (4,512,100) -> WgT [b][128][512] bf16 zero-pad ----------
__global__ __launch_bounds__(256) void prep_wg_kernel(
    const float* __restrict__ Wg, unsigned short* __restrict__ WgT) {
  int idx = blockIdx.x * 256 + threadIdx.x;   // 1024 blocks
  int b = idx >> 16;
  int r = (idx >> 9) & 127;
  int k = idx & 511;
  float v = (r < 100) ? Wg[(b * 512 + k) * 100 + r] : 0.f;
  WgT[idx] = f2bf(v);
}

// ---------- node kernel: 1024 thr = 16 waves, M=64, BK=128 x 4 chunks --------
// Wave owns 32 hcols -> acc[2][4] = 32 AGPR; ~100 VGPR free under (1024,2).
// Per chunk: convert+swizzled LDS write, pool shfl->psum, reg-prefetch next,
// barrier, xg finalize, MFMA (af streamed from L2).
#define NT_MAX 2050
__global__ __launch_bounds__(1024, 2) void node_kernel(
    const float* __restrict__ x,
    const int* __restrict__ meta,
    const int* __restrict__ perm,
    const unsigned short* __restrict__ W1Tf,
    const float* __restrict__ bn1,
    const float* __restrict__ Wn2,
    const float* __restrict__ bn2,
    unsigned short* __restrict__ xg,
    float* __restrict__ n_head,
    float* __restrict__ n_var) {
  __shared__ __align__(16) unsigned short xfrag[2][8192];  // 2 x 16 KB
  __shared__ __align__(16) float psum[2][16][128];         // 16 KB
  // epilogue: float red[64][17][7] (30464 B) aliased over xfrag

  const int4 cvv = *(const int4*)meta;
  const int cnts[4] = {cvv.x, cvv.y, cvv.z, cvv.w};
  int i = blockIdx.x, branch = -1, permOff = 0, nvalid = 0, pb = 0;
  for (int b = 0; b < 4; ++b) {
    int nt = (cnts[b] + 1) >> 1;
    if (branch < 0 && i < nt) { branch = b; permOff = pb + i * 2; nvalid = min(2, cnts[b] - i * 2); }
    if (branch < 0) i -= nt;
    pb += cnts[b];
  }
  if (branch < 0) return;

  const int t    = threadIdx.x;
  const int lane = t & 63;
  const int w    = t >> 6;        // 0..15, wave owns hcols [w*32, w*32+32)
  const int l15  = lane & 15;
  const int l4   = lane >> 4;

  const int g0 = perm[permOff];
  const int g1 = perm[permOff + (nvalid > 1 ? 1 : 0)];

  // staging geometry: thread -> row sr (0..63), octet so (0..15)
  const int sr = t >> 4;
  const int so = t & 15;
  const float* srcbase = x + ((size_t)(sr >= 32 ? g1 : g0) * 32 + (sr & 31)) * HID + so * 8;
  // swizzled fragment write position
  const int sn = sr >> 4, sl15 = sr & 15, skkl = so >> 2, sl4 = so & 3;
  const int welem = ((sn * 4 + skkl) * 64 + ((sl4 << 4) | (sl15 ^ so))) * 8;

  const unsigned short* wb0 = W1Tf + (size_t)(branch * 32 + w * 2) * 8192 + lane * 8;

  f32x4 acc[2][4];
  #pragma unroll
  for (int m = 0; m < 2; ++m)
    #pragma unroll
    for (int n = 0; n < 4; ++n) acc[m][n] = (f32x4)0.f;

  // prologue: chunk 0 into regs
  float4 p0 = *(const float4*)(srcbase);
  float4 p1 = *(const float4*)(srcbase + 4);

  #pragma unroll
  for (int c = 0; c < 4; ++c) {
    // convert + swizzled fragment write (one ds_write_b128)
    u16x8 ua;
    ua[0]=f2bf(p0.x); ua[1]=f2bf(p0.y); ua[2]=f2bf(p0.z); ua[3]=f2bf(p0.w);
    ua[4]=f2bf(p1.x); ua[5]=f2bf(p1.y); ua[6]=f2bf(p1.z); ua[7]=f2bf(p1.w);
    *(u16x8*)&xfrag[c & 1][welem] = ua;

    // pool partials: reduce over rows w*4..w*4+3 (lane bits 4,5)
    float s[8];
    s[0]=p0.x; s[1]=p0.y; s[2]=p0.z; s[3]=p0.w;
    s[4]=p1.x; s[5]=p1.y; s[6]=p1.z; s[7]=p1.w;
    #pragma unroll
    for (int j = 0; j < 8; ++j) {
      s[j] += __shfl_xor(s[j], 16);
      s[j] += __shfl_xor(s[j], 32);
    }
    if (lane < 16) {
      f32x4 a4; a4[0]=s[0]; a4[1]=s[1]; a4[2]=s[2]; a4[3]=s[3];
      f32x4 b4; b4[0]=s[4]; b4[1]=s[5]; b4[2]=s[6]; b4[3]=s[7];
      *(f32x4*)&psum[c & 1][w][lane * 8]     = a4;
      *(f32x4*)&psum[c & 1][w][lane * 8 + 4] = b4;
    }

    // prefetch next chunk (register loads survive the barrier)
    if (c < 3) {
      p0 = *(const float4*)(srcbase + (c + 1) * 128);
      p1 = *(const float4*)(srcbase + (c + 1) * 128 + 4);
    }
    __syncthreads();

    // finalize xg for this chunk's 128 columns
    if (t < 256) {
      int gg = t >> 7, cc = t & 127;
      if (gg == 0 || nvalid > 1) {
        float sv = 0.f;
        #pragma unroll
        for (int j = 0; j < 8; ++j) sv += psum[c & 1][gg * 8 + j][cc];
        xg[(size_t)(gg ? g1 : g0) * HID + c * 128 + cc] = f2bf(sv * (1.f / 32.f));
      }
    }

    // MFMA on chunk c: 4 kk x (2 af x 4 bfr)
    __builtin_amdgcn_s_setprio(1);
    #pragma unroll
    for (int kk = 0; kk < 4; ++kk) {
      bf16x8 af0 = *(const bf16x8*)(wb0 + (size_t)(c * 4 + kk) * 512);
      bf16x8 af1 = *(const bf16x8*)(wb0 + 8192 + (size_t)(c * 4 + kk) * 512);
      const int rslot = (l4 << 4) | (l15 ^ (kk * 4 + l4));
      bf16x8 bfr[4];
      #pragma unroll
      for (int n = 0; n < 4; ++n)
        bfr[n] = *(const bf16x8*)&xfrag[c & 1][((n * 4 + kk) * 64 + rslot) * 8];
      #pragma unroll
      for (int n = 0; n < 4; ++n) {
        acc[0][n] = mfma_bf16(af0, bfr[n], acc[0][n]);
        acc[1][n] = mfma_bf16(af1, bfr[n], acc[1][n]);
      }
    }
    __builtin_amdgcn_s_setprio(0);
  }

  __syncthreads();   // all xfrag reads done -> safe to alias red over it

  // ---- fused stage 2: per-lane fp32 dot with Wn2 over this lane's 8 hcols ----
  float part[4][6];
  #pragma unroll
  for (int n = 0; n < 4; ++n)
    #pragma unroll
    for (int j = 0; j < 6; ++j) part[n][j] = 0.f;
  const float* W2 = Wn2 + branch * HID * 6;
  const float* B1 = bn1 + branch * HID;
  #pragma unroll
  for (int m = 0; m < 2; ++m) {
    #pragma unroll
    for (int r = 0; r < 4; ++r) {
      int hcol = w * 32 + m * 16 + l4 * 4 + r;
      float b1 = B1[hcol];
      float w2[6];
      #pragma unroll
      for (int j = 0; j < 6; ++j) w2[j] = W2[hcol * 6 + j];
      #pragma unroll
      for (int n = 0; n < 4; ++n) {
        float h = fmaxf(acc[m][n][r] + b1, 0.f);
        #pragma unroll
        for (int j = 0; j < 6; ++j) part[n][j] += h * w2[j];
      }
    }
  }
  #pragma unroll
  for (int n = 0; n < 4; ++n)
    #pragma unroll
    for (int j = 0; j < 6; ++j) {
      part[n][j] += __shfl_xor(part[n][j], 16);
      part[n][j] += __shfl_xor(part[n][j], 32);
    }
  float (*red)[17][7] = (float (*)[17][7])&xfrag[0][0];  // [64][17][7]
  if (lane < 16) {
    #pragma unroll
    for (int n = 0; n < 4; ++n)
      #pragma unroll
      for (int j = 0; j < 6; ++j) red[n * 16 + l15][w][j] = part[n][j];
  }
  __syncthreads();
  if (t < 64) {
    int row = t;
    if (row < nvalid * 32) {
      int node = (row < 32 ? g0 : g1) * 32 + (row & 31);
      #pragma unroll
      for (int j = 0; j < 6; ++j) {
        float sv = bn2[branch * 6 + j];
        #pragma unroll
        for (int ww = 0; ww < 16; ++ww) sv += red[row][ww][j];
        if (j < 3) n_head[(size_t)node * 3 + j] = sv;
        else       n_var[(size_t)node * 3 + (j - 3)] = sv * sv;
      }
    }
  }
}

// ---------- graph stage-1: hg = relu(xg @ Ws + bs), 64 graphs/block ----------
#define GT_MAX 67
__global__ __launch_bounds__(512, 4) void gstage1_kernel(
    const unsigned short* __restrict__ xg,
    const int* __restrict__ meta,
    const int* __restrict__ perm,
    const unsigned short* __restrict__ WsTf,
    const float* __restrict__ bs_,
    unsigned short* __restrict__ hg) {
  __shared__ __align__(16) unsigned short xtile[4 * 16 * 512];
  __shared__ int gidl[64];

  const int4 cv = *(const int4*)meta;
  const int cnts[4] = {cv.x, cv.y, cv.z, cv.w};

  int i = blockIdx.x, branch = -1, permOff = 0, nvalid = 0, pb = 0;
  for (int b = 0; b < 4; ++b) {
    int gt = (cnts[b] + 63) >> 6;
    if (branch < 0 && i < gt) { branch = b; permOff = pb + i * 64; nvalid = min(64, cnts[b] - i * 64); }
    if (branch < 0) i -= gt;
    pb += cnts[b];
  }
  if (branch < 0) return;

  const int t    = threadIdx.x;
  const int lane = t & 63;
  const int w    = t >> 6;
  const int l15  = lane & 15;
  const int l4   = lane >> 4;

  if (t < 64) gidl[t] = perm[permOff + min(t, nvalid - 1)];
  __syncthreads();

  for (int idx = t; idx < 4096; idx += 512) {
    int row = idx >> 6;
    int c8  = (idx & 63) * 8;
    u16x8 v = *(const u16x8*)&xg[(size_t)gidl[row] * HID + c8];
    int kk = c8 >> 5, ln = (c8 >> 3) & 3;
    *(u16x8*)&xtile[(((row >> 4) * 16 + kk) * 64 + ((row & 15) + ln * 16)) * 8] = v;
  }
  __syncthreads();

  f32x4 acc[4][4];
  #pragma unroll
  for (int m = 0; m < 4; ++m)
    #pragma unroll
    for (int n = 0; n < 4; ++n) acc[m][n] = (f32x4)0.f;

  const unsigned short* wbase = WsTf + ((size_t)(branch * 32 + w * 4)) * 8192 + lane * 8;
  const unsigned short* xbase = xtile + lane * 8;
  #pragma unroll
  for (int kk = 0; kk < 16; ++kk) {
    bf16x8 af[4];
    #pragma unroll
    for (int m = 0; m < 4; ++m)
      af[m] = *(const bf16x8*)(wbase + (m * 16 + kk) * 512);
    bf16x8 bfr[4];
    #pragma unroll
    for (int n = 0; n < 4; ++n)
      bfr[n] = *(const bf16x8*)(xbase + (n * 16 + kk) * 512);
    #pragma unroll
    for (int m = 0; m < 4; ++m)
      #pragma unroll
      for (int n = 0; n < 4; ++n)
        acc[m][n] = mfma_bf16(af[m], bfr[n], acc[m][n]);
  }

  const float* B1 = bs_ + branch * HID;
  #pragma unroll
  for (int m = 0; m < 4; ++m) {
    #pragma unroll
    for (int n = 0; n < 4; ++n) {
      int row = n * 16 + l15;
      if (row < nvalid) {
        int g = gidl[row];
        int hcb = w * 64 + m * 16 + l4 * 4;
        ushort4 hv;
        hv.x = f2bf(fmaxf(acc[m][n][0] + B1[hcb + 0], 0.f));
        hv.y = f2bf(fmaxf(acc[m][n][1] + B1[hcb + 1], 0.f));
        hv.z = f2bf(fmaxf(acc[m][n][2] + B1[hcb + 2], 0.f));
        hv.w = f2bf(fmaxf(acc[m][n][3] + B1[hcb + 3], 0.f));
        *(ushort4*)(hg + (size_t)g * HID + hcb) = hv;
      }
    }
  }
}

// ---------- graph stage-2: og = hg @ Wg[b] + bg, 16 graphs/block -------------
#define G2_MAX 259
__global__ __launch_bounds__(256) void gstage2_kernel(
    const int* __restrict__ meta,
    const int* __restrict__ perm,
    const unsigned short* __restrict__ hg,
    const unsigned short* __restrict__ WgT,
    const float* __restrict__ bg,
    float* __restrict__ g_head,
    float* __restrict__ g_var) {
  __shared__ int gidl[16];
  const int4 cv = *(const int4*)meta;
  const int cnts[4] = {cv.x, cv.y, cv.z, cv.w};

  int i = blockIdx.x, branch = -1, permOff = 0, nvalid = 0, pb = 0;
  for (int b = 0; b < 4; ++b) {
    int gt = (cnts[b] + 15) >> 4;
    if (branch < 0 && i < gt) { branch = b; permOff = pb + i * 16; nvalid = min(16, cnts[b] - i * 16); }
    if (branch < 0) i -= gt;
    pb += cnts[b];
  }
  if (branch < 0) return;

  const int t    = threadIdx.x;
  const int lane = t & 63;
  const int w    = t >> 6;
  const int l15  = lane & 15;
  const int l4   = lane >> 4;

  if (t < 16) gidl[t] = perm[permOff + min(t, nvalid - 1)];
  __syncthreads();

  f32x4 acc2[2];
  acc2[0] = (f32x4)0.f; acc2[1] = (f32x4)0.f;
  const unsigned short* arow = hg + (size_t)gidl[l15] * HID + l4 * 8;
  const unsigned short* brow = WgT + ((size_t)branch * 128 + w * 32 + l15) * 512 + l4 * 8;
  #pragma unroll
  for (int ks = 0; ks < 16; ++ks) {
    bf16x8 a  = *(const bf16x8*)(arow + ks * 32);
    bf16x8 b0 = *(const bf16x8*)(brow + ks * 32);
    bf16x8 b1 = *(const bf16x8*)(brow + 16 * 512 + ks * 32);
    acc2[0] = mfma_bf16(a, b0, acc2[0]);
    acc2[1] = mfma_bf16(a, b1, acc2[1]);
  }
  #pragma unroll
  for (int n2 = 0; n2 < 2; ++n2) {
    int j = w * 32 + n2 * 16 + l15;
    if (j < 100) {
      float bias = bg[branch * 100 + j];
      #pragma unroll
      for (int rr = 0; rr < 4; ++rr) {
        int r = l4 * 4 + rr;
        if (r < nvalid) {
          int g = gidl[r];
          float val = acc2[n2][rr] + bias;
          if (j < 50) g_head[(size_t)g * 50 + j] = val;
          else        g_var[(size_t)g * 50 + (j - 50)] = val * val;
        }
      }
    }
  }
}

extern "C" void kernel_launch(void* const* d_in, const int* in_sizes, int n_in,
                              void* d_out, int out_size, void* d_ws, size_t ws_size,
                              hipStream_t stream) {
  const float* x    = (const float*)d_in[0];
  const float* Ws   = (const float*)d_in[1];
  const float* bs   = (const float*)d_in[2];
  const float* Wg   = (const float*)d_in[3];
  const float* bg   = (const float*)d_in[4];
  const float* Wn1  = (const float*)d_in[5];
  const float* bn1  = (const float*)d_in[6];
  const float* Wn2  = (const float*)d_in[7];
  const float* bn2  = (const float*)d_in[8];
  const int* dsid   = (const int*)d_in[10];

  float* out    = (float*)d_out;
  float* g_head = out;
  float* g_var  = out + (size_t)N_GRAPHS * 50;
  float* n_head = out + (size_t)2 * N_GRAPHS * 50;
  float* n_var  = n_head + (size_t)N_NODES * 3;

  char* ws = (char*)d_ws;
  int* perm = (int*)(ws);                                   // 16384
  int* meta = (int*)(ws + 16384);                           // 256
  unsigned short* W1Tf = (unsigned short*)(ws + 16640);     // 2,097,152
  unsigned short* WsTf = (unsigned short*)(ws + 2113792);   // 2,097,152
  unsigned short* WgT  = (unsigned short*)(ws + 4210944);   // 524,288
  unsigned short* xg   = (unsigned short*)(ws + 4735232);   // 4,194,304
  unsigned short* hg   = (unsigned short*)(ws + 8929536);   // 4,194,304
  if (ws_size < 13123840) return;

  bucket_kernel<<<dim3(1), dim3(256), 0, stream>>>(dsid, perm, meta);
  prep_wf_kernel<<<dim3(256), dim3(256), 0, stream>>>(Wn1, Ws, W1Tf, WsTf);
  prep_wg_kernel<<<dim3(1024), dim3(256), 0, stream>>>(Wg, WgT);
  node_kernel<<<dim3(NT_MAX), dim3(1024), 0, stream>>>(
      x, meta, perm, W1Tf, bn1, Wn2, bn2, xg, n_head, n_var);
  gstage1_kernel<<<dim3(GT_MAX), dim3(512), 0, stream>>>(
      xg, meta, perm, WsTf, bs, hg);
  gstage2_kernel<<<dim3(G2_MAX), dim3(256), 0, stream>>>(
      meta, perm, hg, WgT, bg, g_head, g_var);
}